// Round 4
// baseline (104.649 us; speedup 1.0000x reference)
//
#include <hip/hip_runtime.h>
#include <stdint.h>

// MetalQuantizedLinear: out[16,8192] = x[16,8192] @ dequant(W_packed[1024,8192], scales[64,8192])
//   w[k][n] = ((nibble_{k%8} of wp[k/8][n]) - 8) * 0.5 * scales[k/128][n]
//
// DTYPE (established round 3): harness promotes the reference's fp16 tensors to
// FLOAT32 on device (fp16 unsupported: inputs/outputs are {bf16,f32,int} only;
// threshold 0.2625 = 0.02*max|ref| proves _any_bf16 is false). x/scales/out: f32.
//
// Structure: grid 512 x 256. Block = 16 cols; wave wv owns k-quarter [wv*2048,+2048).
// mfma_f32_16x16x32_f16: A = fp16(x) (exact, x came from fp16) packed pairwise
// (x[k+r], x[k+r+4]) via v_cvt_pkrtz; B = (nib-8) exact via 0x6400|nib (=1024+nib)
// minus 1032 (v_pk_add_f16). 0.5*scale per 128-k group applied in f32 on the C frag.
// Wave partials k-reduced through 4KB LDS; wave 0 rounds to fp16 grid (RNE, as the
// reference's astype(float16)) and stores f32.

typedef _Float16 half8  __attribute__((ext_vector_type(8)));
typedef _Float16 half2v __attribute__((ext_vector_type(2)));
typedef float    floatx4 __attribute__((ext_vector_type(4)));

constexpr int Kdim = 8192;
constexpr int Ndim = 8192;

__global__ __launch_bounds__(256, 2) void fused_fp4_gemm(
        const float* __restrict__ x,
        const uint32_t* __restrict__ wp,
        const float* __restrict__ scales,
        float* __restrict__ out) {
    __shared__ float red[4][64][4];   // 4 KB: per-wave partial C fragments

    const int t    = threadIdx.x;
    const int wv   = t >> 6;      // k-quarter
    const int lane = t & 63;
    const int c    = lane & 15;   // A row m, B col n, C col
    const int q    = lane >> 4;   // quad -> k-subblock / C row group
    const int nb   = blockIdx.x;  // 0..511
    const int n0   = nb * 16 + c;

    // Weight word for K-step s (=4g+tt): word-row wv*256 + 4s + q, col n0.
    // Nibble i of word-row R encodes k = 8R + i = wv*2048 + s*32 + q*8 + i.
    const uint32_t* wrow = wp + (size_t)(wv * 256 + q) * Ndim + n0;
    // A elements for K-step s: x[c][wv*2048 + s*32 + q*8 + 0..7] (f32, 32B).
    const float* xrow = x + (size_t)c * Kdim + wv * 2048 + q * 8;
    // Scale for group g: scales[wv*16 + g][n0].
    const float* srow = scales + (size_t)(wv * 16) * Ndim + n0;

    uint32_t wbuf[4][4];      // rolling: 4 groups of weights in flight
    float4   abuf[2][4][2];   // rolling: 2 groups of A (8 f32 per step)
    float    scbuf[3];        // rolling: scales 2 ahead

#pragma unroll
    for (int g0 = 0; g0 < 3; ++g0)
#pragma unroll
        for (int tt = 0; tt < 4; ++tt)
            wbuf[g0][tt] = wrow[(size_t)(16 * g0 + 4 * tt) * Ndim];
#pragma unroll
    for (int tt = 0; tt < 4; ++tt) {
        abuf[0][tt][0] = *reinterpret_cast<const float4*>(xrow + tt * 32);
        abuf[0][tt][1] = *reinterpret_cast<const float4*>(xrow + tt * 32 + 4);
    }
    scbuf[0] = 0.5f * srow[0];
    scbuf[1] = 0.5f * srow[(size_t)Ndim];

    floatx4 accm = {0.f, 0.f, 0.f, 0.f};

#pragma unroll
    for (int g = 0; g < 16; ++g) {
        const int gw = (g + 3 < 16) ? g + 3 : 15;   // clamped prefetch (dup = L2 hit)
#pragma unroll
        for (int tt = 0; tt < 4; ++tt)
            wbuf[(g + 3) & 3][tt] = wrow[(size_t)(16 * gw + 4 * tt) * Ndim];
        const int ga = (g + 1 < 16) ? g + 1 : 15;
#pragma unroll
        for (int tt = 0; tt < 4; ++tt) {
            abuf[(g + 1) & 1][tt][0] =
                *reinterpret_cast<const float4*>(xrow + (4 * ga + tt) * 32);
            abuf[(g + 1) & 1][tt][1] =
                *reinterpret_cast<const float4*>(xrow + (4 * ga + tt) * 32 + 4);
        }
        const int gs = (g + 2 < 16) ? g + 2 : 15;
        scbuf[(g + 2) % 3] = 0.5f * srow[(size_t)gs * Ndim];

        floatx4 accg = {0.f, 0.f, 0.f, 0.f};
#pragma unroll
        for (int tt = 0; tt < 4; ++tt) {
            float4 alo = abuf[g & 1][tt][0];   // k-offsets 0..3
            float4 ahi = abuf[g & 1][tt][1];   // k-offsets 4..7
            union { uint32_t u[4]; half8 h; } af, bf;
            // A frag reg r = fp16 pair (x[+r], x[+r+4]) — exact (x was fp16)
            af.u[0] = __builtin_bit_cast(uint32_t, __builtin_amdgcn_cvt_pkrtz(alo.x, ahi.x));
            af.u[1] = __builtin_bit_cast(uint32_t, __builtin_amdgcn_cvt_pkrtz(alo.y, ahi.y));
            af.u[2] = __builtin_bit_cast(uint32_t, __builtin_amdgcn_cvt_pkrtz(alo.z, ahi.z));
            af.u[3] = __builtin_bit_cast(uint32_t, __builtin_amdgcn_cvt_pkrtz(alo.w, ahi.w));
            // B frag reg r = fp16 pair (nib_r-8, nib_{r+4}-8), exact:
            // 0x6400|nib = 1024+nib; subtract 1032.
            const uint32_t w = wbuf[g & 3][tt];
            const half2v koff = {(_Float16)1032.0f, (_Float16)1032.0f};
#pragma unroll
            for (int r = 0; r < 4; ++r) {
                uint32_t m = ((w >> (4 * r)) & 0x000F000Fu) | 0x64006400u;
                half2v p = __builtin_bit_cast(half2v, m) - koff;
                bf.u[r] = __builtin_bit_cast(uint32_t, p);
            }
            accg = __builtin_amdgcn_mfma_f32_16x16x32_f16(af.h, bf.h, accg, 0, 0, 0);
        }
        const float sc = scbuf[g % 3];
#pragma unroll
        for (int r = 0; r < 4; ++r)
            accm[r] = fmaf(sc, accg[r], accm[r]);
    }

    // Cross-wave k-reduction via LDS.
    *reinterpret_cast<float4*>(&red[wv][lane][0]) =
        make_float4(accm[0], accm[1], accm[2], accm[3]);
    __syncthreads();

    if (wv == 0) {
        float4 s0 = *reinterpret_cast<const float4*>(&red[0][lane][0]);
        float4 s1 = *reinterpret_cast<const float4*>(&red[1][lane][0]);
        float4 s2 = *reinterpret_cast<const float4*>(&red[2][lane][0]);
        float4 s3 = *reinterpret_cast<const float4*>(&red[3][lane][0]);
        float v[4] = { s0.x + s1.x + s2.x + s3.x,
                       s0.y + s1.y + s2.y + s3.y,
                       s0.z + s1.z + s2.z + s3.z,
                       s0.w + s1.w + s2.w + s3.w };
        // C/D layout (verified): col = lane&15, row = (lane>>4)*4 + r.
        // Round through fp16 (RNE) to match reference's astype(float16).
#pragma unroll
        for (int r = 0; r < 4; ++r)
            out[(size_t)(q * 4 + r) * Ndim + n0] = (float)(_Float16)v[r];
    }
}

extern "C" void kernel_launch(void* const* d_in, const int* in_sizes, int n_in,
                              void* d_out, int out_size, void* d_ws, size_t ws_size,
                              hipStream_t stream) {
    const float*    xx     = (const float*)d_in[0];
    const uint32_t* wpk    = (const uint32_t*)d_in[1];
    const float*    scales = (const float*)d_in[2];
    float*          outp   = (float*)d_out;

    fused_fp4_gemm<<<512, 256, 0, stream>>>(xx, wpk, scales, outp);
}

// Round 5
// 90.558 us; speedup vs baseline: 1.1556x; 1.1556x over previous
//
#include <hip/hip_runtime.h>
#include <stdint.h>

// MetalQuantizedLinear: out[16,8192] = x[16,8192] @ dequant(W_packed[1024,8192], scales[64,8192])
//   w[k][n] = ((nibble_{k%8} of wp[k/8][n]) - 8) * 0.5 * scales[k/128][n]
//
// DTYPE (verified round 4, passed): x/scales/out are FLOAT32 on device (harness
// promotes the reference's fp16). absmax 0.0156 with exact-dequant f16 MFMA path.
// HARNESS (round 4 profile): ws_size ~= 268 MB; timed loop contains ~95us of
// harness fills/restores; kernel dispatch itself is < 42us (absent from top-5).
//
// Structure: grid 256 x 512 (8 waves). Block = 32 cols; wave wv owns k-eighth
// [wv*1024,+1024) = 8 groups. Lane owns cols n0=nb*32+2c and n0+1 (uint2 weight
// loads -> 128B/quad segments; one A-frag feeds two MFMAs).
// mfma_f32_16x16x32_f16: A = fp16(x) exact via v_cvt_pkrtz pairs (x[+r],x[+r+4]);
// B = (nib-8) exact via (0x6400|nib) - 1032 (v_pk_add_f16). 0.5*scale per 128-k
// group applied in f32 on the C frag. 8-wave k-reduction via 16KB LDS; waves 0/1
// round to fp16 grid (RNE, matching reference astype(float16)) and store f32.

typedef _Float16 half8  __attribute__((ext_vector_type(8)));
typedef _Float16 half2v __attribute__((ext_vector_type(2)));
typedef float    floatx4 __attribute__((ext_vector_type(4)));

constexpr int Kdim = 8192;
constexpr int Ndim = 8192;

__global__ __launch_bounds__(512, 2) void fused_fp4_gemm(
        const float* __restrict__ x,
        const uint32_t* __restrict__ wp,
        const float* __restrict__ scales,
        float* __restrict__ out) {
    __shared__ float red[8][2][64][4];   // 16 KB: per-wave partial C frags, 2 tiles

    const int t    = threadIdx.x;
    const int wv   = t >> 6;      // k-eighth 0..7
    const int lane = t & 63;
    const int c    = lane & 15;   // A row m; col pair index
    const int q    = lane >> 4;   // quad -> k-subblock / C row group
    const int nb   = blockIdx.x;  // 0..255
    const int n0   = nb * 32 + 2 * c;   // tile0 col; tile1 col = n0+1

    // Weight words for K-step s (=4g+tt): word-row wv*128 + 16g + 4tt + q,
    // cols (n0, n0+1) as one uint2. Row stride = Ndim/2 uint2.
    const uint2* wrow = reinterpret_cast<const uint2*>(wp) + ((size_t)(wv * 128 + q) * Ndim + n0) / 2;
    // A elements for K-step s: x[c][wv*1024 + s*32 + q*8 + 0..7].
    const float* xrow = x + (size_t)c * Kdim + wv * 1024 + q * 8;
    // Scales for group g: scales[wv*8 + g][n0, n0+1]. Row stride Ndim/2 float2.
    const float2* srow = reinterpret_cast<const float2*>(scales) + ((size_t)(wv * 8) * Ndim + n0) / 2;

    uint2  wbuf[4][4];      // rolling: 4 groups of weights in flight (3 ahead)
    float4 abuf[2][4][2];   // rolling: 2 groups of A (8 f32 per step)
    float2 scbuf[3];        // rolling: scales 2 ahead

#pragma unroll
    for (int g0 = 0; g0 < 3; ++g0)
#pragma unroll
        for (int tt = 0; tt < 4; ++tt)
            wbuf[g0][tt] = wrow[(size_t)(16 * g0 + 4 * tt) * (Ndim / 2)];
#pragma unroll
    for (int tt = 0; tt < 4; ++tt) {
        abuf[0][tt][0] = *reinterpret_cast<const float4*>(xrow + tt * 32);
        abuf[0][tt][1] = *reinterpret_cast<const float4*>(xrow + tt * 32 + 4);
    }
    scbuf[0] = srow[0];
    scbuf[1] = srow[(size_t)(Ndim / 2)];

    floatx4 accm0 = {0.f, 0.f, 0.f, 0.f};
    floatx4 accm1 = {0.f, 0.f, 0.f, 0.f};

#pragma unroll
    for (int g = 0; g < 8; ++g) {
        const int gw = (g + 3 < 8) ? g + 3 : 7;   // clamped prefetch (dup = cache hit)
#pragma unroll
        for (int tt = 0; tt < 4; ++tt)
            wbuf[(g + 3) & 3][tt] = wrow[(size_t)(16 * gw + 4 * tt) * (Ndim / 2)];
        const int ga = (g + 1 < 8) ? g + 1 : 7;
#pragma unroll
        for (int tt = 0; tt < 4; ++tt) {
            abuf[(g + 1) & 1][tt][0] =
                *reinterpret_cast<const float4*>(xrow + (4 * ga + tt) * 32);
            abuf[(g + 1) & 1][tt][1] =
                *reinterpret_cast<const float4*>(xrow + (4 * ga + tt) * 32 + 4);
        }
        const int gs = (g + 2 < 8) ? g + 2 : 7;
        scbuf[(g + 2) % 3] = srow[(size_t)gs * (Ndim / 2)];

        floatx4 accg0 = {0.f, 0.f, 0.f, 0.f};
        floatx4 accg1 = {0.f, 0.f, 0.f, 0.f};
#pragma unroll
        for (int tt = 0; tt < 4; ++tt) {
            float4 alo = abuf[g & 1][tt][0];   // k-offsets 0..3
            float4 ahi = abuf[g & 1][tt][1];   // k-offsets 4..7
            union { uint32_t u[4]; half8 h; } af, bf0, bf1;
            // A frag reg r = fp16 pair (x[+r], x[+r+4]) — exact (x was fp16)
            af.u[0] = __builtin_bit_cast(uint32_t, __builtin_amdgcn_cvt_pkrtz(alo.x, ahi.x));
            af.u[1] = __builtin_bit_cast(uint32_t, __builtin_amdgcn_cvt_pkrtz(alo.y, ahi.y));
            af.u[2] = __builtin_bit_cast(uint32_t, __builtin_amdgcn_cvt_pkrtz(alo.z, ahi.z));
            af.u[3] = __builtin_bit_cast(uint32_t, __builtin_amdgcn_cvt_pkrtz(alo.w, ahi.w));
            // B frag reg r = fp16 pair (nib_r-8, nib_{r+4}-8), exact:
            // 0x6400|nib = 1024+nib; subtract 1032.
            const uint2 w = wbuf[g & 3][tt];
            const half2v koff = {(_Float16)1032.0f, (_Float16)1032.0f};
#pragma unroll
            for (int r = 0; r < 4; ++r) {
                uint32_t m0 = ((w.x >> (4 * r)) & 0x000F000Fu) | 0x64006400u;
                uint32_t m1 = ((w.y >> (4 * r)) & 0x000F000Fu) | 0x64006400u;
                bf0.u[r] = __builtin_bit_cast(uint32_t, __builtin_bit_cast(half2v, m0) - koff);
                bf1.u[r] = __builtin_bit_cast(uint32_t, __builtin_bit_cast(half2v, m1) - koff);
            }
            accg0 = __builtin_amdgcn_mfma_f32_16x16x32_f16(af.h, bf0.h, accg0, 0, 0, 0);
            accg1 = __builtin_amdgcn_mfma_f32_16x16x32_f16(af.h, bf1.h, accg1, 0, 0, 0);
        }
        const float2 sc = scbuf[g % 3];
#pragma unroll
        for (int r = 0; r < 4; ++r) {
            accm0[r] = fmaf(0.5f * sc.x, accg0[r], accm0[r]);
            accm1[r] = fmaf(0.5f * sc.y, accg1[r], accm1[r]);
        }
    }

    // Cross-wave k-reduction via LDS.
    *reinterpret_cast<float4*>(&red[wv][0][lane][0]) =
        make_float4(accm0[0], accm0[1], accm0[2], accm0[3]);
    *reinterpret_cast<float4*>(&red[wv][1][lane][0]) =
        make_float4(accm1[0], accm1[1], accm1[2], accm1[3]);
    __syncthreads();

    if (wv < 2) {   // wave wv reduces tile wv
        float v[4] = {0.f, 0.f, 0.f, 0.f};
#pragma unroll
        for (int s = 0; s < 8; ++s) {
            float4 p = *reinterpret_cast<const float4*>(&red[s][wv][lane][0]);
            v[0] += p.x; v[1] += p.y; v[2] += p.z; v[3] += p.w;
        }
        // C/D layout (verified): col = lane&15 -> global col n0+wv; row = q*4+r.
        // Round through fp16 (RNE) to match reference's astype(float16).
#pragma unroll
        for (int r = 0; r < 4; ++r)
            out[(size_t)(q * 4 + r) * Ndim + n0 + wv] = (float)(_Float16)v[r];
    }
}

extern "C" void kernel_launch(void* const* d_in, const int* in_sizes, int n_in,
                              void* d_out, int out_size, void* d_ws, size_t ws_size,
                              hipStream_t stream) {
    const float*    xx     = (const float*)d_in[0];
    const uint32_t* wpk    = (const uint32_t*)d_in[1];
    const float*    scales = (const float*)d_in[2];
    float*          outp   = (float*)d_out;

    fused_fp4_gemm<<<256, 512, 0, stream>>>(xx, wpk, scales, outp);
}

// Round 6
// 83.256 us; speedup vs baseline: 1.2570x; 1.0877x over previous
//
#include <hip/hip_runtime.h>
#include <stdint.h>

// MetalQuantizedLinear: out[16,8192] = x[16,8192] @ dequant(W_packed[1024,8192], scales[64,8192])
//   w[k][n] = ((nibble_{k%8} of wp[k/8][n]) - 8) * 0.5 * scales[k/128][n]
//
// DTYPE (verified r4/r5, passing): x/scales/out are FLOAT32 on device.
// HARNESS (r4/r5 profiles): ws_size ~= 268 MB (43us poison fill dominates top-5);
// dur_us carries ~55-85us of fixed harness work; kernel share < 42.7us.
//
// r6 change: A-fragment PREPACK. r5's A-loads put m on lane&15 -> every dwordx4
// touched 16 rows stride 32KB (64 scattered 16B requests/instr, TA-serialized).
// Prepack kernel writes fp16 A-frags to d_ws in gemm order once; gemm A-loads
// become linear coalesced dwordx4 (addr = wv*2048 + step*64 + lane) and the
// per-step cvt_pkrtz ops vanish.
//
// Gemm (structure verified r5): grid 256 x 512 (8 waves). Block = 32 cols; wave
// wv owns k-eighth [wv*1024,+1024) = 8 groups. Lane owns cols n0, n0+1 (uint2
// weight loads -> 128B/quad). mfma_f32_16x16x32_f16: A = fp16(x) exact, pairs
// (x[+r], x[+r+4]); B = (nib-8) exact via (0x6400|nib)-1032. 0.5*scale per group
// in f32 on C. 8-wave LDS k-reduction; waves 0/1 round through fp16 (RNE) to f32.

typedef _Float16 half8  __attribute__((ext_vector_type(8)));
typedef _Float16 half2v __attribute__((ext_vector_type(2)));
typedef float    floatx4 __attribute__((ext_vector_type(4)));

constexpr int Kdim = 8192;
constexpr int Ndim = 8192;

// ---------------------------------------------------------------------------
// Prepack: xp[sq] (16B, sq = m + 16*(k/8)) holds fp16 pairs (x[m][8s+r], x[m][8s+r+4]).
// Linear write xp[tid]; read is 16-row scattered but runs once (16K threads).
// ---------------------------------------------------------------------------
__global__ void prepack_a(const float* __restrict__ x, uint4* __restrict__ xp) {
    int tid = blockIdx.x * 256 + threadIdx.x;   // 0..16383
    int m  = tid & 15;
    int sq = tid >> 4;                          // k-octet index 0..1023
    const float4* x4 = reinterpret_cast<const float4*>(x);
    float4 lo = x4[(size_t)m * (Kdim / 4) + sq * 2];      // k 8sq+0..3
    float4 hi = x4[(size_t)m * (Kdim / 4) + sq * 2 + 1];  // k 8sq+4..7
    uint4 o;
    o.x = __builtin_bit_cast(uint32_t, __builtin_amdgcn_cvt_pkrtz(lo.x, hi.x));
    o.y = __builtin_bit_cast(uint32_t, __builtin_amdgcn_cvt_pkrtz(lo.y, hi.y));
    o.z = __builtin_bit_cast(uint32_t, __builtin_amdgcn_cvt_pkrtz(lo.z, hi.z));
    o.w = __builtin_bit_cast(uint32_t, __builtin_amdgcn_cvt_pkrtz(lo.w, hi.w));
    xp[tid] = o;   // xp index sq*16 + m == tid  (coalesced)
}

__global__ __launch_bounds__(512, 2) void fused_fp4_gemm(
        const uint4* __restrict__ xp,
        const uint32_t* __restrict__ wp,
        const float* __restrict__ scales,
        float* __restrict__ out) {
    __shared__ float red[8][2][64][4];   // 16 KB: per-wave partial C frags, 2 tiles

    const int t    = threadIdx.x;
    const int wv   = t >> 6;      // k-eighth 0..7
    const int lane = t & 63;
    const int c    = lane & 15;   // A row m; col pair index
    const int q    = lane >> 4;   // quad -> k-subblock / C row group
    const int nb   = blockIdx.x;  // 0..255
    const int n0   = nb * 32 + 2 * c;   // tile0 col; tile1 col = n0+1

    // Weight words for K-step s (=4g+tt): word-row wv*128 + 4s + q, cols (n0,n0+1).
    const uint2* wrow = reinterpret_cast<const uint2*>(wp) + ((size_t)(wv * 128 + q) * Ndim + n0) / 2;
    // A frags: xp[(wv*128 + 4s + q)*16 + c] = xp[wv*2048 + s*64 + lane]. Linear!
    const uint4* abase = xp + wv * 2048 + lane;
    // Scales for group g: scales[wv*8 + g][n0, n0+1].
    const float2* srow = reinterpret_cast<const float2*>(scales) + ((size_t)(wv * 8) * Ndim + n0) / 2;

    uint2  wbuf[4][4];      // rolling: 4 groups of weights in flight (3 ahead)
    uint4  abuf[2][4];      // rolling: 2 groups of A frags
    float2 scbuf[3];        // rolling: scales 2 ahead

#pragma unroll
    for (int g0 = 0; g0 < 3; ++g0)
#pragma unroll
        for (int tt = 0; tt < 4; ++tt)
            wbuf[g0][tt] = wrow[(size_t)(16 * g0 + 4 * tt) * (Ndim / 2)];
#pragma unroll
    for (int tt = 0; tt < 4; ++tt) abuf[0][tt] = abase[tt * 64];
    scbuf[0] = srow[0];
    scbuf[1] = srow[(size_t)(Ndim / 2)];

    floatx4 accm0 = {0.f, 0.f, 0.f, 0.f};
    floatx4 accm1 = {0.f, 0.f, 0.f, 0.f};

#pragma unroll
    for (int g = 0; g < 8; ++g) {
        const int gw = (g + 3 < 8) ? g + 3 : 7;   // clamped prefetch (dup = cache hit)
#pragma unroll
        for (int tt = 0; tt < 4; ++tt)
            wbuf[(g + 3) & 3][tt] = wrow[(size_t)(16 * gw + 4 * tt) * (Ndim / 2)];
        const int ga = (g + 1 < 8) ? g + 1 : 7;
#pragma unroll
        for (int tt = 0; tt < 4; ++tt)
            abuf[(g + 1) & 1][tt] = abase[(4 * ga + tt) * 64];
        const int gs = (g + 2 < 8) ? g + 2 : 7;
        scbuf[(g + 2) % 3] = srow[(size_t)gs * (Ndim / 2)];

        floatx4 accg0 = {0.f, 0.f, 0.f, 0.f};
        floatx4 accg1 = {0.f, 0.f, 0.f, 0.f};
#pragma unroll
        for (int tt = 0; tt < 4; ++tt) {
            half8 af = __builtin_bit_cast(half8, abuf[g & 1][tt]);
            // B frag reg r = fp16 pair (nib_r-8, nib_{r+4}-8), exact:
            // 0x6400|nib = 1024+nib; subtract 1032.
            const uint2 w = wbuf[g & 3][tt];
            const half2v koff = {(_Float16)1032.0f, (_Float16)1032.0f};
            union { uint32_t u[4]; half8 h; } bf0, bf1;
#pragma unroll
            for (int r = 0; r < 4; ++r) {
                uint32_t m0 = ((w.x >> (4 * r)) & 0x000F000Fu) | 0x64006400u;
                uint32_t m1 = ((w.y >> (4 * r)) & 0x000F000Fu) | 0x64006400u;
                bf0.u[r] = __builtin_bit_cast(uint32_t, __builtin_bit_cast(half2v, m0) - koff);
                bf1.u[r] = __builtin_bit_cast(uint32_t, __builtin_bit_cast(half2v, m1) - koff);
            }
            accg0 = __builtin_amdgcn_mfma_f32_16x16x32_f16(af, bf0.h, accg0, 0, 0, 0);
            accg1 = __builtin_amdgcn_mfma_f32_16x16x32_f16(af, bf1.h, accg1, 0, 0, 0);
        }
        const float2 sc = scbuf[g % 3];
#pragma unroll
        for (int r = 0; r < 4; ++r) {
            accm0[r] = fmaf(0.5f * sc.x, accg0[r], accm0[r]);
            accm1[r] = fmaf(0.5f * sc.y, accg1[r], accm1[r]);
        }
    }

    // Cross-wave k-reduction via LDS.
    *reinterpret_cast<float4*>(&red[wv][0][lane][0]) =
        make_float4(accm0[0], accm0[1], accm0[2], accm0[3]);
    *reinterpret_cast<float4*>(&red[wv][1][lane][0]) =
        make_float4(accm1[0], accm1[1], accm1[2], accm1[3]);
    __syncthreads();

    if (wv < 2) {   // wave wv reduces tile wv
        float v[4] = {0.f, 0.f, 0.f, 0.f};
#pragma unroll
        for (int s = 0; s < 8; ++s) {
            float4 p = *reinterpret_cast<const float4*>(&red[s][wv][lane][0]);
            v[0] += p.x; v[1] += p.y; v[2] += p.z; v[3] += p.w;
        }
        // C/D layout (verified): col = lane&15 -> global col n0+wv; row = q*4+r.
        // Round through fp16 (RNE) to match reference's astype(float16).
#pragma unroll
        for (int r = 0; r < 4; ++r)
            out[(size_t)(q * 4 + r) * Ndim + n0 + wv] = (float)(_Float16)v[r];
    }
}

extern "C" void kernel_launch(void* const* d_in, const int* in_sizes, int n_in,
                              void* d_out, int out_size, void* d_ws, size_t ws_size,
                              hipStream_t stream) {
    const float*    xx     = (const float*)d_in[0];
    const uint32_t* wpk    = (const uint32_t*)d_in[1];
    const float*    scales = (const float*)d_in[2];
    float*          outp   = (float*)d_out;
    uint4*          xp     = (uint4*)d_ws;   // 256 KB of the ~268 MB workspace

    prepack_a<<<64, 256, 0, stream>>>(xx, xp);
    fused_fp4_gemm<<<256, 512, 0, stream>>>(xp, wpk, scales, outp);
}